// Round 1
// baseline (1075.332 us; speedup 1.0000x reference)
//
#include <hip/hip_runtime.h>
#include <hip/hip_bf16.h>
#include <stdint.h>

#define DEV_INLINE __device__ __forceinline__

typedef __attribute__((ext_vector_type(4))) float f32x4;
typedef __attribute__((ext_vector_type(8))) __bf16 bf16x8;
typedef __attribute__((ext_vector_type(8))) unsigned short u16x8;

// problem dims
constexpr int Bb = 2, Ss = 2048, HIDc = 4096;
constexpr int Hh = 32, KVc = 8, Dd = 128, Gg = 4, Nn = 16, RHc = 1024;

DEV_INLINE unsigned short f32_to_bf16(float f) {
  unsigned u = __float_as_uint(f);
  u += 0x7fffu + ((u >> 16) & 1u);   // round-to-nearest-even
  return (unsigned short)(u >> 16);
}
DEV_INLINE float bf16_lo(unsigned u) { return __uint_as_float(u << 16); }
DEV_INLINE float bf16_hi(unsigned u) { return __uint_as_float(u & 0xffff0000u); }

// ---------------- cast f32 -> bf16 (optionally scaled) ----------------
__global__ void cast_f32_bf16_kernel(const float* __restrict__ src,
                                     unsigned short* __restrict__ dst,
                                     int n4, float scale) {
  int i = blockIdx.x * blockDim.x + threadIdx.x;
  int stride = gridDim.x * blockDim.x;
  const f32x4* s4 = reinterpret_cast<const f32x4*>(src);
  ushort4* d4 = reinterpret_cast<ushort4*>(dst);
  for (; i < n4; i += stride) {
    f32x4 v = s4[i];
    ushort4 o;
    o.x = f32_to_bf16(v.x * scale);
    o.y = f32_to_bf16(v.y * scale);
    o.z = f32_to_bf16(v.z * scale);
    o.w = f32_to_bf16(v.w * scale);
    d4[i] = o;
  }
}

// ---------------- GEMM: C[M][N] = A[M][K] * B[N][K]^T (bf16 in, f32 acc) ----
// m97 structure: 128x128 tile, BK=32, 256 threads (4 waves 2x2), 4x4 16x16x32
// MFMA fragments per wave, global_load_lds width-16 staging, 2 barriers/K-step.
template <bool OUT_BF16>
__global__ __launch_bounds__(256) void gemm_bt_kernel(
    const unsigned short* __restrict__ A,   // [M][K] bf16
    const unsigned short* __restrict__ Bw,  // [N][K] bf16
    void* __restrict__ Cout,                // [M][N] f32 or bf16
    int M, int N, int K) {
  __shared__ alignas(16) unsigned short As[128 * 32];
  __shared__ alignas(16) unsigned short Bs[128 * 32];
  const int tid = threadIdx.x;
  const int wave = tid >> 6;
  const int lane = tid & 63;
  const int wr = wave >> 1, wc = wave & 1;
  const long arow0 = (long)blockIdx.y * 128;
  const long bcol0 = (long)blockIdx.x * 128;

  const unsigned short* Abase = A + arow0 * K;
  const unsigned short* Bbase = Bw + bcol0 * K;

  const int lrow = lane & 15;          // fragment row within 16
  const int lk = (lane >> 4) << 3;     // fragment k-offset (8 elems)

  f32x4 acc[4][4];
#pragma unroll
  for (int m = 0; m < 4; ++m)
#pragma unroll
    for (int n = 0; n < 4; ++n) acc[m][n] = {0.f, 0.f, 0.f, 0.f};

  for (int k0 = 0; k0 < K; k0 += 32) {
    // stage A and B 128x32 tiles into LDS: 512 16B chunks each, 2 insts/thread
#pragma unroll
    for (int j = 0; j < 2; ++j) {
      int c = j * 256 + tid;
      int row = c >> 2;
      int kp = (c & 3) << 3;
      int ldsoff = (j * 256 + wave * 64) * 16;  // bytes; wave-uniform base
      const unsigned short* ga = Abase + (long)row * K + k0 + kp;
      const unsigned short* gb = Bbase + (long)row * K + k0 + kp;
      __builtin_amdgcn_global_load_lds(
          (const __attribute__((address_space(1))) unsigned int*)ga,
          (__attribute__((address_space(3))) unsigned int*)((char*)As + ldsoff),
          16, 0, 0);
      __builtin_amdgcn_global_load_lds(
          (const __attribute__((address_space(1))) unsigned int*)gb,
          (__attribute__((address_space(3))) unsigned int*)((char*)Bs + ldsoff),
          16, 0, 0);
    }
    __syncthreads();  // drains vmcnt -> LDS tiles ready

    bf16x8 afr[4], bfr[4];
#pragma unroll
    for (int m = 0; m < 4; ++m)
      afr[m] = *reinterpret_cast<const bf16x8*>(
          &As[(wr * 64 + m * 16 + lrow) * 32 + lk]);
#pragma unroll
    for (int n = 0; n < 4; ++n)
      bfr[n] = *reinterpret_cast<const bf16x8*>(
          &Bs[(wc * 64 + n * 16 + lrow) * 32 + lk]);
#pragma unroll
    for (int m = 0; m < 4; ++m)
#pragma unroll
      for (int n = 0; n < 4; ++n)
        acc[m][n] = __builtin_amdgcn_mfma_f32_16x16x32_bf16(afr[m], bfr[n],
                                                            acc[m][n], 0, 0, 0);
    __syncthreads();  // protect LDS before next stage
  }

  // epilogue: C/D layout col = lane&15, row = (lane>>4)*4 + r
  const int rbase = (lane >> 4) << 2;
  const int cbase = lane & 15;
#pragma unroll
  for (int m = 0; m < 4; ++m) {
#pragma unroll
    for (int n = 0; n < 4; ++n) {
      long r0 = arow0 + wr * 64 + m * 16 + rbase;
      long c0 = bcol0 + wc * 64 + n * 16 + cbase;
#pragma unroll
      for (int r = 0; r < 4; ++r) {
        float v = acc[m][n][r];
        if constexpr (OUT_BF16)
          ((unsigned short*)Cout)[(r0 + r) * N + c0] = f32_to_bf16(v);
        else
          ((float*)Cout)[(r0 + r) * N + c0] = v;
      }
    }
  }
}

// ---------------- grouped neighbor attention ----------------
// one wave per (b*s, kv); lane = g*16 + i
// k[b,s,kv,i,d] = Kf[(bs*16 + 2*kv + (i>>3))][ (i&7)*128 + d ]
__global__ __launch_bounds__(256) void attn_kernel(
    const unsigned short* __restrict__ Q,   // [B*S][H*D] bf16 (pre-scaled)
    const unsigned short* __restrict__ Kf,  // [B*S*N][KV*D] bf16
    const unsigned short* __restrict__ Vf,  // [B*S*N][KV*D] bf16
    unsigned short* __restrict__ O) {       // [B*S][H*D] bf16
  const int tid = threadIdx.x;
  const int wave = tid >> 6;
  const int lane = tid & 63;
  const int sl = blockIdx.x * 4 + wave;  // [0, B*S*KV)
  const int bs = sl >> 3;
  const int kv = sl & 7;
  const int g = lane >> 4;
  const int i = lane & 15;

  const unsigned short* qrow = Q + (long)bs * (Hh * Dd) + (kv * Gg + g) * Dd;
  const int ni = 2 * kv + (i >> 3);
  const unsigned short* krow =
      Kf + ((long)bs * Nn + ni) * (KVc * Dd) + (i & 7) * Dd;

  float s = 0.f;
#pragma unroll
  for (int c = 0; c < 16; ++c) {
    uint4 qu = *reinterpret_cast<const uint4*>(qrow + c * 8);
    uint4 ku = *reinterpret_cast<const uint4*>(krow + c * 8);
    s += bf16_lo(qu.x) * bf16_lo(ku.x) + bf16_hi(qu.x) * bf16_hi(ku.x);
    s += bf16_lo(qu.y) * bf16_lo(ku.y) + bf16_hi(qu.y) * bf16_hi(ku.y);
    s += bf16_lo(qu.z) * bf16_lo(ku.z) + bf16_hi(qu.z) * bf16_hi(ku.z);
    s += bf16_lo(qu.w) * bf16_lo(ku.w) + bf16_hi(qu.w) * bf16_hi(ku.w);
  }

  // softmax across the 16-lane group (over neighbor index i)
  float mx = s;
#pragma unroll
  for (int off = 8; off >= 1; off >>= 1) mx = fmaxf(mx, __shfl_xor(mx, off));
  float p = __expf(s - mx);
  float sum = p;
#pragma unroll
  for (int off = 8; off >= 1; off >>= 1) sum += __shfl_xor(sum, off);
  p = p / sum;

  // PV: lane (g,i) accumulates out[g][i*8 .. i*8+7]
  float o[8] = {0.f, 0.f, 0.f, 0.f, 0.f, 0.f, 0.f, 0.f};
  const long vbase = (long)bs * Nn * (KVc * Dd);
#pragma unroll
  for (int ii = 0; ii < 16; ++ii) {
    float pi = __shfl(p, (lane & 48) | ii);
    const unsigned short* vrow = Vf + vbase +
        (long)(2 * kv + (ii >> 3)) * (KVc * Dd) + (ii & 7) * Dd + i * 8;
    uint4 vu = *reinterpret_cast<const uint4*>(vrow);
    o[0] += pi * bf16_lo(vu.x); o[1] += pi * bf16_hi(vu.x);
    o[2] += pi * bf16_lo(vu.y); o[3] += pi * bf16_hi(vu.y);
    o[4] += pi * bf16_lo(vu.z); o[5] += pi * bf16_hi(vu.z);
    o[6] += pi * bf16_lo(vu.w); o[7] += pi * bf16_hi(vu.w);
  }
  u16x8 ov;
#pragma unroll
  for (int d = 0; d < 8; ++d) ov[d] = f32_to_bf16(o[d]);
  *reinterpret_cast<u16x8*>(O + (long)bs * (Hh * Dd) + (kv * Gg + g) * Dd +
                            i * 8) = ov;
}

// ---------------- launch ----------------
extern "C" void kernel_launch(void* const* d_in, const int* in_sizes, int n_in,
                              void* d_out, int out_size, void* d_ws,
                              size_t ws_size, hipStream_t stream) {
  (void)in_sizes; (void)n_in; (void)out_size; (void)ws_size;
  const float* hs = (const float*)d_in[0];   // [2,2048,4096]
  const float* rhs = (const float*)d_in[1];  // [2,2048,16,1024]
  const float* Wq = (const float*)d_in[2];   // [4096,4096]
  const float* Wk = (const float*)d_in[3];   // [1024,1024]
  const float* Wv = (const float*)d_in[4];   // [1024,1024]
  const float* Wo = (const float*)d_in[5];   // [4096,4096]
  float* out = (float*)d_out;                // [2,2048,4096] f32

  char* ws = (char*)d_ws;
  size_t off = 0;
  auto alloc = [&](size_t bytes) { char* p = ws + off; off += bytes; return p; };
  unsigned short* hsb  = (unsigned short*)alloc(16777216ull * 2);
  unsigned short* Wqb  = (unsigned short*)alloc(16777216ull * 2);
  unsigned short* rhsb = (unsigned short*)alloc(67108864ull * 2);
  unsigned short* Wkb  = (unsigned short*)alloc(1048576ull * 2);
  unsigned short* Wvb  = (unsigned short*)alloc(1048576ull * 2);
  unsigned short* Wob  = (unsigned short*)alloc(16777216ull * 2);
  unsigned short* Qb   = (unsigned short*)alloc(16777216ull * 2);
  unsigned short* Kb   = (unsigned short*)alloc(67108864ull * 2);
  unsigned short* Vb   = (unsigned short*)alloc(67108864ull * 2);
  unsigned short* Ab   = (unsigned short*)alloc(16777216ull * 2);

  const float scaler = 0.08838834764831845f;  // D^-0.5, folded into Wq

  cast_f32_bf16_kernel<<<2048, 256, 0, stream>>>(hs, hsb, 16777216 / 4, 1.f);
  cast_f32_bf16_kernel<<<2048, 256, 0, stream>>>(Wq, Wqb, 16777216 / 4, scaler);
  cast_f32_bf16_kernel<<<4096, 256, 0, stream>>>(rhs, rhsb, 67108864 / 4, 1.f);
  cast_f32_bf16_kernel<<<512, 256, 0, stream>>>(Wk, Wkb, 1048576 / 4, 1.f);
  cast_f32_bf16_kernel<<<512, 256, 0, stream>>>(Wv, Wvb, 1048576 / 4, 1.f);
  cast_f32_bf16_kernel<<<2048, 256, 0, stream>>>(Wo, Wob, 16777216 / 4, 1.f);

  // Q = hs @ Wq^T (scaled), bf16 out
  gemm_bt_kernel<true><<<dim3(4096 / 128, 4096 / 128), 256, 0, stream>>>(
      hsb, Wqb, Qb, 4096, 4096, 4096);
  // K = rhs_flat @ Wk^T ; V = rhs_flat @ Wv^T
  gemm_bt_kernel<true><<<dim3(1024 / 128, 65536 / 128), 256, 0, stream>>>(
      rhsb, Wkb, Kb, 65536, 1024, 1024);
  gemm_bt_kernel<true><<<dim3(1024 / 128, 65536 / 128), 256, 0, stream>>>(
      rhsb, Wvb, Vb, 65536, 1024, 1024);
  // grouped neighbor attention
  attn_kernel<<<8192, 256, 0, stream>>>(Qb, Kb, Vb, Ab);
  // out = attn @ Wo^T, f32 out
  gemm_bt_kernel<false><<<dim3(4096 / 128, 4096 / 128), 256, 0, stream>>>(
      Ab, Wob, out, 4096, 4096, 4096);
}

// Round 2
// 864.410 us; speedup vs baseline: 1.2440x; 1.2440x over previous
//
#include <hip/hip_runtime.h>
#include <hip/hip_bf16.h>
#include <stdint.h>

#define DEV_INLINE __device__ __forceinline__

typedef __attribute__((ext_vector_type(4))) float f32x4;
typedef __attribute__((ext_vector_type(8))) __bf16 bf16x8;
typedef __attribute__((ext_vector_type(8))) unsigned short u16x8;

// problem dims
constexpr int Hh = 32, KVc = 8, Dd = 128, Gg = 4, Nn = 16;

DEV_INLINE unsigned short f32_to_bf16(float f) {
  unsigned u = __float_as_uint(f);
  u += 0x7fffu + ((u >> 16) & 1u);   // round-to-nearest-even
  return (unsigned short)(u >> 16);
}
DEV_INLINE float bf16_lo(unsigned u) { return __uint_as_float(u << 16); }
DEV_INLINE float bf16_hi(unsigned u) { return __uint_as_float(u & 0xffff0000u); }

// ---------------- cast f32 -> bf16 (optionally scaled) ----------------
__global__ void cast_f32_bf16_kernel(const float* __restrict__ src,
                                     unsigned short* __restrict__ dst,
                                     int n4, float scale) {
  int i = blockIdx.x * blockDim.x + threadIdx.x;
  int stride = gridDim.x * blockDim.x;
  const f32x4* s4 = reinterpret_cast<const f32x4*>(src);
  ushort4* d4 = reinterpret_cast<ushort4*>(dst);
  for (; i < n4; i += stride) {
    f32x4 v = s4[i];
    ushort4 o;
    o.x = f32_to_bf16(v.x * scale);
    o.y = f32_to_bf16(v.y * scale);
    o.z = f32_to_bf16(v.z * scale);
    o.w = f32_to_bf16(v.w * scale);
    d4[i] = o;
  }
}

// ---------------- GEMM: C[M][N] = A[M][K] * B[N][K]^T ----------------
// 256x256 tile, BK=32, 512 threads (8 waves 2m x 4n), ring-4 LDS double-
// buffering with counted vmcnt (never drained in main loop), per-phase
// {ds_read || global_load_lds -> s_barrier -> lgkmcnt(0) -> setprio+16 MFMA ->
// s_barrier} interleave, XOR bank-swizzle applied to staging source + ds_read.
template <bool OUT_BF16>
__global__ __launch_bounds__(512) void gemm256_kernel(
    const unsigned short* __restrict__ A,   // [M][K] bf16
    const unsigned short* __restrict__ Bw,  // [N][K] bf16
    void* __restrict__ Cout,                // [M][N] f32 or bf16
    int M, int N, int K) {
  __shared__ alignas(16) unsigned short Als[4][256 * 32];
  __shared__ alignas(16) unsigned short Bls[4][256 * 32];
  const int tid = threadIdx.x;
  const int wave = tid >> 6, lane = tid & 63;
  const int wm = wave >> 2, wn = wave & 3;       // 2 x 4 wave grid
  const int lrow = lane & 15, lhi = lane >> 4;
  // swizzled 16B-slot byte offset for fragment reads (involution: slot ^= (row>>1)&3)
  const int swslot = (lhi ^ ((lrow >> 1) & 3)) << 4;

  // XCD-aware block swizzle (T1); all our grids are % 8 == 0
  const int ntn = N >> 8;
  const int nwg = gridDim.x, bid = blockIdx.x;
  const int swz = ((nwg & 7) == 0) ? ((bid & 7) * (nwg >> 3) + (bid >> 3)) : bid;
  const int tm = swz / ntn, tn = swz - tm * ntn;

  const unsigned short* Abase = A + (long)tm * 256 * K;
  const unsigned short* Bbase = Bw + (long)tn * 256 * K;
  const int ktiles = K >> 5;

  // stage one 256x32 bf16 tile; linear LDS dest, inverse-swizzled global src
  auto stage = [&](const unsigned short* gbase, unsigned short* lslot, int k0) {
#pragma unroll
    for (int j = 0; j < 2; ++j) {
      int c = (j << 9) + tid;              // chunk 0..1023 (16B each)
      int row = c >> 2;
      int gslot = (c & 3) ^ ((row >> 1) & 3);
      const unsigned short* g = gbase + (long)row * K + k0 + (gslot << 3);
      int ldsoff = (((j << 9) + (wave << 6)) << 4);  // wave-uniform base
      __builtin_amdgcn_global_load_lds(
          (const __attribute__((address_space(1))) unsigned int*)g,
          (__attribute__((address_space(3))) unsigned int*)((char*)lslot + ldsoff),
          16, 0, 0);
    }
  };

  f32x4 acc[8][4];
#pragma unroll
  for (int m = 0; m < 8; ++m)
#pragma unroll
    for (int n = 0; n < 4; ++n) acc[m][n] = {0.f, 0.f, 0.f, 0.f};

  // prologue: stage tiles 0..2 (12 loads/thread), wait so tile 0 landed
#pragma unroll
  for (int p = 0; p < 3; ++p) {
    if (p < ktiles) {
      stage(Abase, Als[p], p << 5);
      stage(Bbase, Bls[p], p << 5);
    }
  }
  if (ktiles > 2) asm volatile("s_waitcnt vmcnt(8)" ::: "memory");
  else            asm volatile("s_waitcnt vmcnt(0)" ::: "memory");
  __builtin_amdgcn_s_barrier();

  bf16x8 afr[4], bfr[4];
  for (int t = 0; t < ktiles; ++t) {
    const int slot = t & 3, ps = (t + 3) & 3;
    const char* Ac = (const char*)Als[slot];
    const char* Bc = (const char*)Bls[slot];

    // ---- phase 0: B frags (all n) + A frags m0-3, stage A(t+3) ----
#pragma unroll
    for (int n = 0; n < 4; ++n)
      bfr[n] = *reinterpret_cast<const bf16x8*>(
          Bc + (((wn << 6) + (n << 4) + lrow) << 6) + swslot);
#pragma unroll
    for (int m = 0; m < 4; ++m)
      afr[m] = *reinterpret_cast<const bf16x8*>(
          Ac + (((wm << 7) + (m << 4) + lrow) << 6) + swslot);
    if (t + 3 < ktiles) stage(Abase, Als[ps], (t + 3) << 5);
    __builtin_amdgcn_s_barrier();
    asm volatile("s_waitcnt lgkmcnt(0)");
    __builtin_amdgcn_s_setprio(1);
#pragma unroll
    for (int m = 0; m < 4; ++m)
#pragma unroll
      for (int n = 0; n < 4; ++n)
        acc[m][n] = __builtin_amdgcn_mfma_f32_16x16x32_bf16(afr[m], bfr[n],
                                                            acc[m][n], 0, 0, 0);
    __builtin_amdgcn_s_setprio(0);
    __builtin_amdgcn_s_barrier();

    // ---- phase 1: A frags m4-7, stage B(t+3) ----
#pragma unroll
    for (int m = 0; m < 4; ++m)
      afr[m] = *reinterpret_cast<const bf16x8*>(
          Ac + (((wm << 7) + 64 + (m << 4) + lrow) << 6) + swslot);
    if (t + 3 < ktiles) stage(Bbase, Bls[ps], (t + 3) << 5);
    __builtin_amdgcn_s_barrier();
    asm volatile("s_waitcnt lgkmcnt(0)");
    __builtin_amdgcn_s_setprio(1);
#pragma unroll
    for (int m = 0; m < 4; ++m)
#pragma unroll
      for (int n = 0; n < 4; ++n)
        acc[m + 4][n] = __builtin_amdgcn_mfma_f32_16x16x32_bf16(
            afr[m], bfr[n], acc[m + 4][n], 0, 0, 0);
    __builtin_amdgcn_s_setprio(0);
    // end-of-tile wait: next tile (t+1) fully landed; keep 8 loads in flight
    if (t + 3 < ktiles)      asm volatile("s_waitcnt vmcnt(8)" ::: "memory");
    else if (t + 2 < ktiles) asm volatile("s_waitcnt vmcnt(4)" ::: "memory");
    else if (t + 1 < ktiles) asm volatile("s_waitcnt vmcnt(0)" ::: "memory");
    __builtin_amdgcn_s_barrier();
  }

  // epilogue: C/D layout col = lane&15, row = (lane>>4)*4 + r
#pragma unroll
  for (int m = 0; m < 8; ++m) {
#pragma unroll
    for (int n = 0; n < 4; ++n) {
      long r0 = (long)tm * 256 + (wm << 7) + (m << 4) + (lhi << 2);
      long c0 = (long)tn * 256 + (wn << 6) + (n << 4) + lrow;
#pragma unroll
      for (int r = 0; r < 4; ++r) {
        float v = acc[m][n][r];
        if constexpr (OUT_BF16)
          ((unsigned short*)Cout)[(r0 + r) * N + c0] = f32_to_bf16(v);
        else
          ((float*)Cout)[(r0 + r) * N + c0] = v;
      }
    }
  }
}

// ---------------- grouped neighbor attention ----------------
// one wave per (b*s, kv); lane = g*16 + i
__global__ __launch_bounds__(256) void attn_kernel(
    const unsigned short* __restrict__ Q,   // [B*S][H*D] bf16 (pre-scaled)
    const unsigned short* __restrict__ Kf,  // [B*S*N][KV*D] bf16
    const unsigned short* __restrict__ Vf,  // [B*S*N][KV*D] bf16
    unsigned short* __restrict__ O) {       // [B*S][H*D] bf16
  const int tid = threadIdx.x;
  const int wave = tid >> 6;
  const int lane = tid & 63;
  const int sl = blockIdx.x * 4 + wave;  // [0, B*S*KV)
  const int bs = sl >> 3;
  const int kv = sl & 7;
  const int g = lane >> 4;
  const int i = lane & 15;

  const unsigned short* qrow = Q + (long)bs * (Hh * Dd) + (kv * Gg + g) * Dd;
  const int ni = 2 * kv + (i >> 3);
  const unsigned short* krow =
      Kf + ((long)bs * Nn + ni) * (KVc * Dd) + (i & 7) * Dd;

  float s = 0.f;
#pragma unroll
  for (int c = 0; c < 16; ++c) {
    uint4 qu = *reinterpret_cast<const uint4*>(qrow + c * 8);
    uint4 ku = *reinterpret_cast<const uint4*>(krow + c * 8);
    s += bf16_lo(qu.x) * bf16_lo(ku.x) + bf16_hi(qu.x) * bf16_hi(ku.x);
    s += bf16_lo(qu.y) * bf16_lo(ku.y) + bf16_hi(qu.y) * bf16_hi(ku.y);
    s += bf16_lo(qu.z) * bf16_lo(ku.z) + bf16_hi(qu.z) * bf16_hi(ku.z);
    s += bf16_lo(qu.w) * bf16_lo(ku.w) + bf16_hi(qu.w) * bf16_hi(ku.w);
  }

  float mx = s;
#pragma unroll
  for (int off = 8; off >= 1; off >>= 1) mx = fmaxf(mx, __shfl_xor(mx, off));
  float p = __expf(s - mx);
  float sum = p;
#pragma unroll
  for (int off = 8; off >= 1; off >>= 1) sum += __shfl_xor(sum, off);
  p = p / sum;

  float o[8] = {0.f, 0.f, 0.f, 0.f, 0.f, 0.f, 0.f, 0.f};
  const long vbase = (long)bs * Nn * (KVc * Dd);
#pragma unroll
  for (int ii = 0; ii < 16; ++ii) {
    float pi = __shfl(p, (lane & 48) | ii);
    const unsigned short* vrow = Vf + vbase +
        (long)(2 * kv + (ii >> 3)) * (KVc * Dd) + (ii & 7) * Dd + i * 8;
    uint4 vu = *reinterpret_cast<const uint4*>(vrow);
    o[0] += pi * bf16_lo(vu.x); o[1] += pi * bf16_hi(vu.x);
    o[2] += pi * bf16_lo(vu.y); o[3] += pi * bf16_hi(vu.y);
    o[4] += pi * bf16_lo(vu.z); o[5] += pi * bf16_hi(vu.z);
    o[6] += pi * bf16_lo(vu.w); o[7] += pi * bf16_hi(vu.w);
  }
  u16x8 ov;
#pragma unroll
  for (int d = 0; d < 8; ++d) ov[d] = f32_to_bf16(o[d]);
  *reinterpret_cast<u16x8*>(O + (long)bs * (Hh * Dd) + (kv * Gg + g) * Dd +
                            i * 8) = ov;
}

// ---------------- launch ----------------
extern "C" void kernel_launch(void* const* d_in, const int* in_sizes, int n_in,
                              void* d_out, int out_size, void* d_ws,
                              size_t ws_size, hipStream_t stream) {
  (void)in_sizes; (void)n_in; (void)out_size; (void)ws_size;
  const float* hs = (const float*)d_in[0];   // [2,2048,4096]
  const float* rhs = (const float*)d_in[1];  // [2,2048,16,1024]
  const float* Wq = (const float*)d_in[2];   // [4096,4096]
  const float* Wk = (const float*)d_in[3];   // [1024,1024]
  const float* Wv = (const float*)d_in[4];   // [1024,1024]
  const float* Wo = (const float*)d_in[5];   // [4096,4096]
  float* out = (float*)d_out;                // [2,2048,4096] f32

  char* ws = (char*)d_ws;
  size_t off = 0;
  auto alloc = [&](size_t bytes) { char* p = ws + off; off += bytes; return p; };
  unsigned short* hsb  = (unsigned short*)alloc(16777216ull * 2);
  unsigned short* Wqb  = (unsigned short*)alloc(16777216ull * 2);
  unsigned short* rhsb = (unsigned short*)alloc(67108864ull * 2);
  unsigned short* Wkb  = (unsigned short*)alloc(1048576ull * 2);
  unsigned short* Wvb  = (unsigned short*)alloc(1048576ull * 2);
  unsigned short* Wob  = (unsigned short*)alloc(16777216ull * 2);
  unsigned short* Qb   = (unsigned short*)alloc(16777216ull * 2);
  unsigned short* Kb   = (unsigned short*)alloc(67108864ull * 2);
  unsigned short* Vb   = (unsigned short*)alloc(67108864ull * 2);
  unsigned short* Ab   = (unsigned short*)alloc(16777216ull * 2);

  const float scaler = 0.08838834764831845f;  // D^-0.5, folded into Wq

  cast_f32_bf16_kernel<<<2048, 256, 0, stream>>>(hs, hsb, 16777216 / 4, 1.f);
  cast_f32_bf16_kernel<<<2048, 256, 0, stream>>>(Wq, Wqb, 16777216 / 4, scaler);
  cast_f32_bf16_kernel<<<4096, 256, 0, stream>>>(rhs, rhsb, 67108864 / 4, 1.f);
  cast_f32_bf16_kernel<<<512, 256, 0, stream>>>(Wk, Wkb, 1048576 / 4, 1.f);
  cast_f32_bf16_kernel<<<512, 256, 0, stream>>>(Wv, Wvb, 1048576 / 4, 1.f);
  cast_f32_bf16_kernel<<<2048, 256, 0, stream>>>(Wo, Wob, 16777216 / 4, 1.f);

  // Q = hs @ Wq^T (scaled), bf16 out   — grid 16x16 = 256 blocks
  gemm256_kernel<true><<<256, 512, 0, stream>>>(hsb, Wqb, Qb, 4096, 4096, 4096);
  // K,V = rhs_flat @ Wk/Wv^T           — grid 256x4 = 1024 blocks
  gemm256_kernel<true><<<1024, 512, 0, stream>>>(rhsb, Wkb, Kb, 65536, 1024, 1024);
  gemm256_kernel<true><<<1024, 512, 0, stream>>>(rhsb, Wvb, Vb, 65536, 1024, 1024);
  // grouped neighbor attention
  attn_kernel<<<8192, 256, 0, stream>>>(Qb, Kb, Vb, Ab);
  // out = attn @ Wo^T, f32 out
  gemm256_kernel<false><<<256, 512, 0, stream>>>(Ab, Wob, out, 4096, 4096, 4096);
}

// Round 3
// 829.232 us; speedup vs baseline: 1.2968x; 1.0424x over previous
//
#include <hip/hip_runtime.h>
#include <hip/hip_bf16.h>
#include <stdint.h>

#define DEV_INLINE __device__ __forceinline__

typedef __attribute__((ext_vector_type(4))) float f32x4;
typedef __attribute__((ext_vector_type(8))) __bf16 bf16x8;
typedef __attribute__((ext_vector_type(8))) unsigned short u16x8;

// problem dims
constexpr int Hh = 32, KVc = 8, Dd = 128, Gg = 4, Nn = 16;

DEV_INLINE unsigned short f32_to_bf16(float f) {
  unsigned u = __float_as_uint(f);
  u += 0x7fffu + ((u >> 16) & 1u);   // round-to-nearest-even
  return (unsigned short)(u >> 16);
}
DEV_INLINE float bf16_lo(unsigned u) { return __uint_as_float(u << 16); }
DEV_INLINE float bf16_hi(unsigned u) { return __uint_as_float(u & 0xffff0000u); }

// ---------------- cast f32 -> bf16 (optionally scaled) ----------------
__global__ void cast_f32_bf16_kernel(const float* __restrict__ src,
                                     unsigned short* __restrict__ dst,
                                     int n4, float scale) {
  int i = blockIdx.x * blockDim.x + threadIdx.x;
  int stride = gridDim.x * blockDim.x;
  const f32x4* s4 = reinterpret_cast<const f32x4*>(src);
  ushort4* d4 = reinterpret_cast<ushort4*>(dst);
  for (; i < n4; i += stride) {
    f32x4 v = s4[i];
    ushort4 o;
    o.x = f32_to_bf16(v.x * scale);
    o.y = f32_to_bf16(v.y * scale);
    o.z = f32_to_bf16(v.z * scale);
    o.w = f32_to_bf16(v.w * scale);
    d4[i] = o;
  }
}

// ---------------- GEMM: C[M][N] = A[M][K] * B[N][K]^T ----------------
// 256x256 tile, BK=32, 512 threads (8 waves 2m x 4n), ring-4 LDS, 2-tile
// unrolled K-loop with register-level fragment double-buffering: each phase
// {issue next frags' ds_reads || issue 1 stage -> counted lgkmcnt (older reads
// only) -> setprio+16 MFMA -> counted vmcnt -> s_barrier}. ds_read latency is
// hidden under the previous phase's MFMA cluster; vmcnt never drains to 0 in
// steady state.
template <bool OUT_BF16>
__global__ __launch_bounds__(512, 2) void gemm256_kernel(
    const unsigned short* __restrict__ A,   // [M][K] bf16
    const unsigned short* __restrict__ Bw,  // [N][K] bf16
    void* __restrict__ Cout,                // [M][N] f32 or bf16
    int M, int N, int K) {
  __shared__ alignas(16) unsigned short Als[4][256 * 32];
  __shared__ alignas(16) unsigned short Bls[4][256 * 32];
  const int tid = threadIdx.x;
  const int wave = tid >> 6, lane = tid & 63;
  const int wm = wave >> 2, wn = wave & 3;       // 2 x 4 wave grid
  const int lrow = lane & 15, lhi = lane >> 4;
  // swizzled 16B-slot byte offset for fragment reads (involution with stage)
  const int swslot = (lhi ^ ((lrow >> 1) & 3)) << 4;

  // XCD-aware block swizzle (T1); all our grids are % 8 == 0
  const int ntn = N >> 8;
  const int nwg = gridDim.x, bid = blockIdx.x;
  const int swz = ((nwg & 7) == 0) ? ((bid & 7) * (nwg >> 3) + (bid >> 3)) : bid;
  const int tm = swz / ntn, tn = swz - tm * ntn;

  const unsigned short* Abase = A + (long)tm * 256 * K;
  const unsigned short* Bbase = Bw + (long)tn * 256 * K;
  const int ktiles = K >> 5;   // always even here (128 or 32)

  // stage one 256x32 bf16 tile; linear LDS dest, inverse-swizzled global src
  auto stage = [&](const unsigned short* gbase, unsigned short* lslot, int k0) {
#pragma unroll
    for (int j = 0; j < 2; ++j) {
      int c = (j << 9) + tid;              // chunk 0..1023 (16B each)
      int row = c >> 2;
      int gslot = (c & 3) ^ ((row >> 1) & 3);
      const unsigned short* g = gbase + (long)row * K + k0 + (gslot << 3);
      int ldsoff = (((j << 9) + (wave << 6)) << 4);  // wave-uniform base
      __builtin_amdgcn_global_load_lds(
          (const __attribute__((address_space(1))) unsigned int*)g,
          (__attribute__((address_space(3))) unsigned int*)((char*)lslot + ldsoff),
          16, 0, 0);
    }
  };

#define RD_B(dst, Bc)                                                      \
  _Pragma("unroll") for (int n = 0; n < 4; ++n) dst[n] =                   \
      *reinterpret_cast<const bf16x8*>(                                    \
          (Bc) + (((wn << 6) + (n << 4) + lrow) << 6) + swslot);
#define RD_A(dst, Ac, mh)                                                  \
  _Pragma("unroll") for (int m = 0; m < 4; ++m) dst[m] =                   \
      *reinterpret_cast<const bf16x8*>(                                    \
          (Ac) + (((wm << 7) + ((mh) << 6) + (m << 4) + lrow) << 6) + swslot);
#define MFMA16(accrow, af, bf)                                             \
  _Pragma("unroll") for (int m = 0; m < 4; ++m)                            \
  _Pragma("unroll") for (int n = 0; n < 4; ++n)                            \
      acc[(accrow) + m][n] = __builtin_amdgcn_mfma_f32_16x16x32_bf16(      \
          af[m], bf[n], acc[(accrow) + m][n], 0, 0, 0);

  f32x4 acc[8][4];
#pragma unroll
  for (int m = 0; m < 8; ++m)
#pragma unroll
    for (int n = 0; n < 4; ++n) acc[m][n] = {0.f, 0.f, 0.f, 0.f};

  // prologue: stage tiles 0..2, wait tile 0 landed, prefetch slot-0 frags
#pragma unroll
  for (int p = 0; p < 3; ++p) {
    if (p < ktiles) {
      stage(Abase, Als[p], p << 5);
      stage(Bbase, Bls[p], p << 5);
    }
  }
  if (ktiles > 2) asm volatile("s_waitcnt vmcnt(8)" ::: "memory");
  else            asm volatile("s_waitcnt vmcnt(0)" ::: "memory");
  __builtin_amdgcn_s_barrier();

  bf16x8 bfrE[4], afrE[4], bfrO[4], afrO[4], afrH[4];
  RD_B(bfrE, (const char*)Bls[0]);
  RD_A(afrE, (const char*)Als[0], 0);

  for (int t0 = 0; t0 < ktiles; t0 += 2) {
    const int t1 = t0 + 1;
    const char* Ac0 = (const char*)Als[t0 & 3];
    const char* Bc0 = (const char*)Bls[t0 & 3];
    const char* Ac1 = (const char*)Als[t1 & 3];
    const char* Bc1 = (const char*)Bls[t1 & 3];
    const int sp = (t0 + 3) & 3;   // ring slot for tiles t0+3 / t1+3

    // ---- P0: MFMA tile t0 m0-3; prefetch A m4-7(t0); stage A(t0+3) ----
    RD_A(afrH, Ac0, 1);
    if (t0 + 3 < ktiles) stage(Abase, Als[sp], (t0 + 3) << 5);
    asm volatile("s_waitcnt lgkmcnt(4)" ::: "memory");  // bfrE/afrE ready
    __builtin_amdgcn_s_setprio(1);
    MFMA16(0, afrE, bfrE);
    __builtin_amdgcn_s_setprio(0);
    if (t0 + 3 < ktiles)      asm volatile("s_waitcnt vmcnt(6)" ::: "memory");
    else if (t0 + 2 < ktiles) asm volatile("s_waitcnt vmcnt(4)" ::: "memory");
    else                      asm volatile("s_waitcnt vmcnt(0)" ::: "memory");
    __builtin_amdgcn_s_barrier();   // tile t1 landed for everyone

    // ---- P1: MFMA tile t0 m4-7; prefetch frags(t1); stage B(t0+3) ----
    RD_B(bfrO, Bc1);
    RD_A(afrO, Ac1, 0);
    if (t0 + 3 < ktiles) stage(Bbase, Bls[sp], (t0 + 3) << 5);
    asm volatile("s_waitcnt lgkmcnt(8)" ::: "memory");  // afrH ready
    __builtin_amdgcn_s_setprio(1);
    MFMA16(4, afrH, bfrE);
    __builtin_amdgcn_s_setprio(0);
    __builtin_amdgcn_s_barrier();   // slot (t0-1) reads done -> P2 stage safe

    // ---- P2: MFMA tile t1 m0-3; prefetch A m4-7(t1); stage A(t1+3) ----
    RD_A(afrH, Ac1, 1);
    if (t1 + 3 < ktiles) stage(Abase, Als[t0 & 3], (t1 + 3) << 5);
    asm volatile("s_waitcnt lgkmcnt(4)" ::: "memory");  // bfrO/afrO ready
    __builtin_amdgcn_s_setprio(1);
    MFMA16(0, afrO, bfrO);
    __builtin_amdgcn_s_setprio(0);
    if (t1 + 3 < ktiles)      asm volatile("s_waitcnt vmcnt(6)" ::: "memory");
    else if (t1 + 2 < ktiles) asm volatile("s_waitcnt vmcnt(4)" ::: "memory");
    else                      asm volatile("s_waitcnt vmcnt(0)" ::: "memory");
    __builtin_amdgcn_s_barrier();   // tile t0+2 landed for everyone

    // ---- P3: MFMA tile t1 m4-7; prefetch frags(t0+2); stage B(t1+3) ----
    if (t0 + 2 < ktiles) {
      const char* Bc2 = (const char*)Bls[(t0 + 2) & 3];
      const char* Ac2 = (const char*)Als[(t0 + 2) & 3];
      RD_B(bfrE, Bc2);
      RD_A(afrE, Ac2, 0);
    }
    if (t1 + 3 < ktiles) stage(Bbase, Bls[t0 & 3], (t1 + 3) << 5);
    if (t0 + 2 < ktiles) asm volatile("s_waitcnt lgkmcnt(8)" ::: "memory");
    else                 asm volatile("s_waitcnt lgkmcnt(0)" ::: "memory");
    __builtin_amdgcn_s_setprio(1);
    MFMA16(4, afrH, bfrO);
    __builtin_amdgcn_s_setprio(0);
    __builtin_amdgcn_s_barrier();   // slot t0 reads done -> next P0 stage safe
  }

  // epilogue: C/D layout col = lane&15, row = (lane>>4)*4 + r
#pragma unroll
  for (int m = 0; m < 8; ++m) {
#pragma unroll
    for (int n = 0; n < 4; ++n) {
      long r0 = (long)tm * 256 + (wm << 7) + (m << 4) + (lhi << 2);
      long c0 = (long)tn * 256 + (wn << 6) + (n << 4) + lrow;
#pragma unroll
      for (int r = 0; r < 4; ++r) {
        float v = acc[m][n][r];
        if constexpr (OUT_BF16)
          ((unsigned short*)Cout)[(r0 + r) * N + c0] = f32_to_bf16(v);
        else
          ((float*)Cout)[(r0 + r) * N + c0] = v;
      }
    }
  }
#undef RD_A
#undef RD_B
#undef MFMA16
}

// ---------------- grouped neighbor attention ----------------
// one wave per (b*s, kv); lane = g*16 + i
__global__ __launch_bounds__(256) void attn_kernel(
    const unsigned short* __restrict__ Q,   // [B*S][H*D] bf16 (pre-scaled)
    const unsigned short* __restrict__ Kf,  // [B*S*N][KV*D] bf16
    const unsigned short* __restrict__ Vf,  // [B*S*N][KV*D] bf16
    unsigned short* __restrict__ O) {       // [B*S][H*D] bf16
  const int tid = threadIdx.x;
  const int wave = tid >> 6;
  const int lane = tid & 63;
  const int sl = blockIdx.x * 4 + wave;  // [0, B*S*KV)
  const int bs = sl >> 3;
  const int kv = sl & 7;
  const int g = lane >> 4;
  const int i = lane & 15;

  const unsigned short* qrow = Q + (long)bs * (Hh * Dd) + (kv * Gg + g) * Dd;
  const int ni = 2 * kv + (i >> 3);
  const unsigned short* krow =
      Kf + ((long)bs * Nn + ni) * (KVc * Dd) + (i & 7) * Dd;

  float s = 0.f;
#pragma unroll
  for (int c = 0; c < 16; ++c) {
    uint4 qu = *reinterpret_cast<const uint4*>(qrow + c * 8);
    uint4 ku = *reinterpret_cast<const uint4*>(krow + c * 8);
    s += bf16_lo(qu.x) * bf16_lo(ku.x) + bf16_hi(qu.x) * bf16_hi(ku.x);
    s += bf16_lo(qu.y) * bf16_lo(ku.y) + bf16_hi(qu.y) * bf16_hi(ku.y);
    s += bf16_lo(qu.z) * bf16_lo(ku.z) + bf16_hi(qu.z) * bf16_hi(ku.z);
    s += bf16_lo(qu.w) * bf16_lo(ku.w) + bf16_hi(qu.w) * bf16_hi(ku.w);
  }

  float mx = s;
#pragma unroll
  for (int off = 8; off >= 1; off >>= 1) mx = fmaxf(mx, __shfl_xor(mx, off));
  float p = __expf(s - mx);
  float sum = p;
#pragma unroll
  for (int off = 8; off >= 1; off >>= 1) sum += __shfl_xor(sum, off);
  p = p / sum;

  float o[8] = {0.f, 0.f, 0.f, 0.f, 0.f, 0.f, 0.f, 0.f};
  const long vbase = (long)bs * Nn * (KVc * Dd);
#pragma unroll
  for (int ii = 0; ii < 16; ++ii) {
    float pi = __shfl(p, (lane & 48) | ii);
    const unsigned short* vrow = Vf + vbase +
        (long)(2 * kv + (ii >> 3)) * (KVc * Dd) + (ii & 7) * Dd + i * 8;
    uint4 vu = *reinterpret_cast<const uint4*>(vrow);
    o[0] += pi * bf16_lo(vu.x); o[1] += pi * bf16_hi(vu.x);
    o[2] += pi * bf16_lo(vu.y); o[3] += pi * bf16_hi(vu.y);
    o[4] += pi * bf16_lo(vu.z); o[5] += pi * bf16_hi(vu.z);
    o[6] += pi * bf16_lo(vu.w); o[7] += pi * bf16_hi(vu.w);
  }
  u16x8 ov;
#pragma unroll
  for (int d = 0; d < 8; ++d) ov[d] = f32_to_bf16(o[d]);
  *reinterpret_cast<u16x8*>(O + (long)bs * (Hh * Dd) + (kv * Gg + g) * Dd +
                            i * 8) = ov;
}

// ---------------- launch ----------------
extern "C" void kernel_launch(void* const* d_in, const int* in_sizes, int n_in,
                              void* d_out, int out_size, void* d_ws,
                              size_t ws_size, hipStream_t stream) {
  (void)in_sizes; (void)n_in; (void)out_size; (void)ws_size;
  const float* hs = (const float*)d_in[0];   // [2,2048,4096]
  const float* rhs = (const float*)d_in[1];  // [2,2048,16,1024]
  const float* Wq = (const float*)d_in[2];   // [4096,4096]
  const float* Wk = (const float*)d_in[3];   // [1024,1024]
  const float* Wv = (const float*)d_in[4];   // [1024,1024]
  const float* Wo = (const float*)d_in[5];   // [4096,4096]
  float* out = (float*)d_out;                // [2,2048,4096] f32

  char* ws = (char*)d_ws;
  size_t off = 0;
  auto alloc = [&](size_t bytes) { char* p = ws + off; off += bytes; return p; };
  unsigned short* hsb  = (unsigned short*)alloc(16777216ull * 2);
  unsigned short* Wqb  = (unsigned short*)alloc(16777216ull * 2);
  unsigned short* rhsb = (unsigned short*)alloc(67108864ull * 2);
  unsigned short* Wkb  = (unsigned short*)alloc(1048576ull * 2);
  unsigned short* Wvb  = (unsigned short*)alloc(1048576ull * 2);
  unsigned short* Wob  = (unsigned short*)alloc(16777216ull * 2);
  unsigned short* Qb   = (unsigned short*)alloc(16777216ull * 2);
  unsigned short* Kb   = (unsigned short*)alloc(67108864ull * 2);
  unsigned short* Vb   = (unsigned short*)alloc(67108864ull * 2);
  unsigned short* Ab   = (unsigned short*)alloc(16777216ull * 2);

  const float scaler = 0.08838834764831845f;  // D^-0.5, folded into Wq

  cast_f32_bf16_kernel<<<2048, 256, 0, stream>>>(hs, hsb, 16777216 / 4, 1.f);
  cast_f32_bf16_kernel<<<2048, 256, 0, stream>>>(Wq, Wqb, 16777216 / 4, scaler);
  cast_f32_bf16_kernel<<<4096, 256, 0, stream>>>(rhs, rhsb, 67108864 / 4, 1.f);
  cast_f32_bf16_kernel<<<512, 256, 0, stream>>>(Wk, Wkb, 1048576 / 4, 1.f);
  cast_f32_bf16_kernel<<<512, 256, 0, stream>>>(Wv, Wvb, 1048576 / 4, 1.f);
  cast_f32_bf16_kernel<<<2048, 256, 0, stream>>>(Wo, Wob, 16777216 / 4, 1.f);

  // Q = hs @ Wq^T (scaled), bf16 out   — grid 16x16 = 256 blocks
  gemm256_kernel<true><<<256, 512, 0, stream>>>(hsb, Wqb, Qb, 4096, 4096, 4096);
  // K,V = rhs_flat @ Wk/Wv^T           — grid 256x4 = 1024 blocks
  gemm256_kernel<true><<<1024, 512, 0, stream>>>(rhsb, Wkb, Kb, 65536, 1024, 1024);
  gemm256_kernel<true><<<1024, 512, 0, stream>>>(rhsb, Wvb, Vb, 65536, 1024, 1024);
  // grouped neighbor attention
  attn_kernel<<<8192, 256, 0, stream>>>(Qb, Kb, Vb, Ab);
  // out = attn @ Wo^T, f32 out
  gemm256_kernel<false><<<256, 512, 0, stream>>>(Ab, Wob, out, 4096, 4096, 4096);
}